// Round 7
// baseline (492.773 us; speedup 1.0000x reference)
//
#include <hip/hip_runtime.h>

#define TT 2048     // sequence length
#define DD 256      // head dim
#define RQB 128     // q-rows per block (8 row-groups x 16)
#define NT 1024     // 16 waves: 8 row-groups x 2 K-halves
#define KB 32       // K-cols per LDS tile (per half)
#define NTILE 32    // tiles per half (1024/32)
#define NITER 30
#define CAP 24      // stored candidates per row PER HALF
#define CAP2 (2 * CAP)

// LDS byte layout: staging [2 halves][2 bufs][16 KB] at 0
#define L_CIDX 65536                      // u16 [RQB][CAP2] = 12 KB
#define L_CVAL (L_CIDX + RQB * CAP2 * 2)  // f32 [RQB][CAP2] = 24 KB
#define L_CNT  (L_CVAL + RQB * CAP2 * 4)  // int [RQB][2]
#define L_SLOT (L_CNT + RQB * 8)          // u16 [16][16*CAP] = 12 KB
#define L_OVF  (L_SLOT + 16 * 16 * CAP * 2)
#define LDS_SZ (L_OVF + 16)               // ~113 KB -> 1 block/CU, 16 waves

typedef __attribute__((ext_vector_type(4))) float f32x4;
typedef __attribute__((ext_vector_type(8))) short short8;

__device__ inline unsigned short f2bf(float x) {     // RTN fp32 -> bf16
    unsigned u = __float_as_uint(x);
    return (unsigned short)((u + 0x7fffu + ((u >> 16) & 1u)) >> 16);
}
__device__ inline float bf2f(unsigned short h) {
    return __uint_as_float((unsigned)h << 16);
}

__device__ __forceinline__ void gload16(const void* g, void* l) {
    __builtin_amdgcn_global_load_lds(
        (const __attribute__((address_space(1))) void*)g,
        (__attribute__((address_space(3))) void*)l, 16, 0, 0);
}

// max over 16-lane group via DPP (VALU-only, no LDS-pipe shuffles)
__device__ __forceinline__ float dppmax16(float m) {
    int a = __builtin_amdgcn_update_dpp(__float_as_int(m), __float_as_int(m),
                                        0xB1, 0xF, 0xF, false);   // quad_perm xor1
    m = fmaxf(m, __int_as_float(a));
    a = __builtin_amdgcn_update_dpp(__float_as_int(m), __float_as_int(m),
                                    0x4E, 0xF, 0xF, false);       // quad_perm xor2
    m = fmaxf(m, __int_as_float(a));
    a = __builtin_amdgcn_update_dpp(__float_as_int(m), __float_as_int(m),
                                    0x141, 0xF, 0xF, false);      // row_half_mirror
    m = fmaxf(m, __int_as_float(a));
    a = __builtin_amdgcn_update_dpp(__float_as_int(m), __float_as_int(m),
                                    0x140, 0xF, 0xF, false);      // row_mirror
    m = fmaxf(m, __int_as_float(a));
    return m;
}

// ---------------- helper: K -> 0.5*K bf16 (screening operand) ----------------
__global__ __launch_bounds__(256) void split_k_kernel(const float* __restrict__ K,
        unsigned short* __restrict__ Kh, int n4) {
    int i = blockIdx.x * 256 + threadIdx.x;
    const int stride = gridDim.x * 256;
    for (; i < n4; i += stride) {
        float4 v = ((const float4*)K)[i];
        unsigned short h0 = f2bf(0.5f * v.x), h1 = f2bf(0.5f * v.y);
        unsigned short h2 = f2bf(0.5f * v.z), h3 = f2bf(0.5f * v.w);
        uint2 hv;
        hv.x = (unsigned)h0 | ((unsigned)h1 << 16);
        hv.y = (unsigned)h2 | ((unsigned)h3 << 16);
        ((uint2*)Kh)[i] = hv;
    }
}

// ---------------- main fused kernel ----------------
__launch_bounds__(NT, 4)
__global__ void entmax_screen_kernel(const float* __restrict__ Q,
                                     const unsigned short* __restrict__ Kh,
                                     const float* __restrict__ Kf,
                                     const float* __restrict__ V,
                                     float* __restrict__ Out,
                                     int nwg) {
    extern __shared__ char smem[];
    unsigned short* CIDX = (unsigned short*)(smem + L_CIDX);
    float*          CVAL = (float*)(smem + L_CVAL);
    int*            CNT  = (int*)(smem + L_CNT);
    unsigned short* SLOT = (unsigned short*)(smem + L_SLOT);
    int*            POVF = (int*)(smem + L_OVF);

    const int tid = threadIdx.x;
    const int wid = tid >> 6, lane = tid & 63;
    const int l15 = lane & 15, ag = lane >> 4;
    const int rg8 = wid & 7;            // row group
    const int hf  = wid >> 3;           // K-half (0: cols 0..1023, 1: 1024..2047)
    const int wrow0 = rg8 * 16;

    // XCD-bijective swizzle (nwg = 256, divisible by 8)
    const int lb = (blockIdx.x & 7) * (nwg >> 3) + (blockIdx.x >> 3);
    const int b  = lb >> 4;
    const int t0 = (lb & 15) * RQB;

    const char* KhB = (const char*)(Kh + (size_t)b * TT * DD);

    if (tid == 0) *POVF = 0;

    // ---- A-fragments: 16 Q rows per wave, single bf16 ----
    short8 ah[8];
    {
        const float* qr = Q + (size_t)(b * TT + t0 + wrow0 + l15) * DD;
        #pragma unroll
        for (int kk = 0; kk < 8; ++kk) {
            const int d0 = kk * 32 + ag * 8;
            float4 qa = *(const float4*)(qr + d0);
            float4 qb = *(const float4*)(qr + d0 + 4);
            float qf[8] = {qa.x, qa.y, qa.z, qa.w, qb.x, qb.y, qb.z, qb.w};
            #pragma unroll
            for (int i = 0; i < 8; ++i) ah[kk][i] = (short)f2bf(qf[i]);
        }
    }

    // ---- hoisted staging addresses (per-lane global base, uniform LDS dest) ----
    const int ofs0 = rg8 * 1024 + lane * 16;            // linear byte in 16 KB tile
    const int cl0 = ofs0 >> 9, wb0 = ofs0 & 511;
    const int ofs1 = ofs0 + 8192;
    const int cl1 = ofs1 >> 9, wb1 = ofs1 & 511;
    const size_t gbb0 = ((size_t)((hf << 10) + cl0) << 9) + (size_t)(wb0 ^ ((cl0 & 7) << 4));
    const size_t gbb1 = ((size_t)((hf << 10) + cl1) << 9) + (size_t)(wb1 ^ ((cl1 & 7) << 4));
    const int wu0 = hf * 32768 + rg8 * 1024;            // wave-uniform LDS base

    auto STAGE = [&](int tile, int buf) {
        const size_t gt = (size_t)tile * 16384;
        gload16(KhB + gbb0 + gt, smem + wu0 + buf * 16384);
        gload16(KhB + gbb1 + gt, smem + wu0 + buf * 16384 + 8192);
    };

    // ---- hoisted swizzled ds_read base pointers (even/odd kk) ----
    const int s_ = (l15 & 7) << 4;
    const int q0 = ((ag * 16) ^ (s_ & 0x30)) | (s_ & 0x40);
    const char* pE = smem + hf * 32768 + l15 * 512 + q0;
    const char* pO = smem + hf * 32768 + l15 * 512 + (q0 ^ 0x40);

    STAGE(0, 0);
    __syncthreads();

    const unsigned long long grpmask = 0xFFFFULL << (ag * 16);
    const unsigned long long lowmask = (lane == 0) ? 0ULL : ((~0ULL) >> (64 - lane));
    float rmax[4];
    int   base[4];
    #pragma unroll
    for (int r = 0; r < 4; ++r) { rmax[r] = -3.402823466e38f; base[r] = 0; }

    // ---------------- screening pass: 32 tiles of 32 cols (this half) ----------------
    for (int t = 0; t < NTILE; ++t) {
        const int cur = t & 1;
        if (t + 1 < NTILE) STAGE(t + 1, cur ^ 1);
        const int coff = cur * 16384;
        f32x4 acc0, acc1;
        #pragma unroll
        for (int r = 0; r < 4; ++r) { acc0[r] = 0.0f; acc1[r] = 0.0f; }
        #pragma unroll
        for (int kk = 0; kk < 8; ++kk) {
            const char* pk = (kk & 1) ? pO : pE;
            const short8 b0 = *(const short8*)(pk + coff + (kk >> 1) * 128);
            const short8 b1 = *(const short8*)(pk + coff + 8192 + (kk >> 1) * 128);
            acc0 = __builtin_amdgcn_mfma_f32_16x16x32_bf16(ah[kk], b0, acc0, 0, 0, 0);
            acc1 = __builtin_amdgcn_mfma_f32_16x16x32_bf16(ah[kk], b1, acc1, 0, 0, 0);
        }
        #pragma unroll
        for (int rg = 0; rg < 4; ++rg) {
            float m = dppmax16(fmaxf(acc0[rg], acc1[rg]));
            rmax[rg] = fmaxf(rmax[rg], m);
            const float thr = rmax[rg] - 1.6f;      // slack covers bf16 screen error
            const int row = wrow0 + ag * 4 + rg;
            {
                const bool p = acc0[rg] > thr;
                const unsigned long long ball = __ballot(p) & grpmask;
                if (ball) {
                    const int rank = (int)__popcll(ball & lowmask);
                    if (p && base[rg] + rank < CAP)
                        CIDX[row * CAP2 + hf * CAP + base[rg] + rank] =
                            (unsigned short)((hf << 10) + (t << 5) + l15);
                    base[rg] += (int)__popcll(ball);
                }
            }
            {
                const bool p = acc1[rg] > thr;
                const unsigned long long ball = __ballot(p) & grpmask;
                if (ball) {
                    const int rank = (int)__popcll(ball & lowmask);
                    if (p && base[rg] + rank < CAP)
                        CIDX[row * CAP2 + hf * CAP + base[rg] + rank] =
                            (unsigned short)((hf << 10) + (t << 5) + 16 + l15);
                    base[rg] += (int)__popcll(ball);
                }
            }
        }
        __syncthreads();
    }

    // publish counts
    #pragma unroll
    for (int rg = 0; rg < 4; ++rg) {
        if (l15 == 0) {
            CNT[(wrow0 + ag * 4 + rg) * 2 + hf] = base[rg];
            if (base[rg] > CAP) *POVF = 1;
        }
    }
    __syncthreads();

    // ---------------- exact fp32 recompute of stored candidates ----------------
    int c = 0;
    if (lane < 16) {
        const int cc = CNT[(wrow0 + lane) * 2 + hf];
        c = cc > CAP ? CAP : cc;
    }
    int x = c;
    #pragma unroll
    for (int off = 1; off < 16; off <<= 1) {
        const int v = __shfl_up(x, off);
        if ((lane & 15) >= off) x += v;
    }
    const int pfx = x - c;
    const int total = __shfl(x, 15);
    if (lane < 16)
        for (int i = 0; i < c; ++i)
            SLOT[wid * (16 * CAP) + pfx + i] = (unsigned short)((lane << 8) | i);
    __syncthreads();

    {
        const float* Qb = Q + (size_t)(b * TT + t0 + wrow0) * DD;
        const float* Kb = Kf + (size_t)b * TT * DD;
        for (int bs = 0; bs < total; bs += 8) {
            float4 qv[8], kv[8];
            int rl[8], ii[8];
            #pragma unroll
            for (int u = 0; u < 8; ++u) {
                const int s = bs + u;
                const int e = (s < total) ? (int)SLOT[wid * (16 * CAP) + s] : 0;
                rl[u] = e >> 8; ii[u] = e & 255;
                const int col = (s < total)
                    ? (int)CIDX[(wrow0 + rl[u]) * CAP2 + hf * CAP + ii[u]] : 0;
                qv[u] = *(const float4*)(Qb + (size_t)rl[u] * DD + lane * 4);
                kv[u] = *(const float4*)(Kb + (size_t)col * DD + lane * 4);
            }
            float sm[8];
            #pragma unroll
            for (int u = 0; u < 8; ++u) {
                float d = qv[u].x * kv[u].x;
                d = fmaf(qv[u].y, kv[u].y, d);
                d = fmaf(qv[u].z, kv[u].z, d);
                d = fmaf(qv[u].w, kv[u].w, d);
                sm[u] = d;
            }
            #pragma unroll
            for (int off = 32; off; off >>= 1)
                #pragma unroll
                for (int u = 0; u < 8; ++u) sm[u] += __shfl_xor(sm[u], off);
            #pragma unroll
            for (int u = 0; u < 8; ++u)
                if (lane == u && bs + u < total)
                    CVAL[(wrow0 + rl[u]) * CAP2 + hf * CAP + ii[u]] = 0.5f * sm[u];
        }
    }
    __syncthreads();

    // ---------------- slow path (CAP overflow; ~never) ----------------
    if (*POVF) {
        if (wid == 0) {
            float* fbz = (float*)smem;          // staging buffers are dead
            for (int r = 0; r < RQB; ++r) {
                if (CNT[r * 2] <= CAP && CNT[r * 2 + 1] <= CAP) continue;
                const float* qr = Q + (size_t)(b * TT + t0 + r) * DD;
                const float* Kb = Kf + (size_t)b * TT * DD;
                for (int cc2 = lane; cc2 < TT; cc2 += 64) {
                    const float* kr = Kb + (size_t)cc2 * DD;
                    float a = 0.0f;
                    for (int d = 0; d < DD; ++d) a = fmaf(qr[d], kr[d], a);
                    fbz[cc2] = 0.5f * a;
                }
                __threadfence_block();
                float m = -3.402823466e38f;
                for (int cc2 = lane; cc2 < TT; cc2 += 64) m = fmaxf(m, fbz[cc2]);
                #pragma unroll
                for (int off = 32; off; off >>= 1) m = fmaxf(m, __shfl_xor(m, off));
                float lo = m - 1.0f, hi = m, tau;
                for (int it = 0; it < NITER; ++it) {
                    tau = 0.5f * (lo + hi);
                    float s = 0.0f;
                    for (int cc2 = lane; cc2 < TT; cc2 += 64) {
                        const float tt2 = fmaxf(fbz[cc2] - tau, 0.0f);
                        s = fmaf(tt2, tt2, s);
                    }
                    #pragma unroll
                    for (int off = 32; off; off >>= 1) s += __shfl_xor(s, off);
                    const bool gt = s > 1.0f;
                    lo = gt ? tau : lo;
                    hi = gt ? hi : tau;
                }
                tau = 0.5f * (lo + hi);
                float ssum = 0.0f;
                for (int cc2 = lane; cc2 < TT; cc2 += 64) {
                    const float tt2 = fmaxf(fbz[cc2] - tau, 0.0f);
                    ssum = fmaf(tt2, tt2, ssum);
                }
                #pragma unroll
                for (int off = 32; off; off >>= 1) ssum += __shfl_xor(ssum, off);
                const float inv = 1.0f / ssum;
                const int d4 = lane * 4;
                float4 o = make_float4(0.f, 0.f, 0.f, 0.f);
                for (int s = 0; s < TT; ++s) {
                    const float tt2 = fmaxf(fbz[s] - tau, 0.0f);
                    const float w = tt2 * tt2 * inv;
                    if (w > 0.0f) {
                        const float4 v = *(const float4*)(V + ((size_t)b * TT + s) * DD + d4);
                        o.x = fmaf(w, v.x, o.x); o.y = fmaf(w, v.y, o.y);
                        o.z = fmaf(w, v.z, o.z); o.w = fmaf(w, v.w, o.w);
                    }
                }
                *(float4*)(Out + ((size_t)(b * TT + t0 + r)) * DD + d4) = o;
                if (lane == 0) CNT[r * 2] = -1;
                __threadfence_block();
            }
        }
        __syncthreads();
    }

    // ---------------- tau + weights + sparse PV (merged halves, 8 rows/wave) ----------------
    const float* Vb = V + (size_t)b * TT * DD;
    for (int jj = 0; jj < 8; ++jj) {
        const int row = wid * 8 + jj;
        const int n0 = CNT[row * 2];
        if (n0 < 0) continue;                  // slow path handled
        const int n0c = n0 > CAP ? CAP : n0;
        const int n1t = CNT[row * 2 + 1];
        const int n1c = n1t > CAP ? CAP : n1t;
        const bool valid = (lane < CAP2) && ((lane < CAP) ? (lane < n0c)
                                                          : (lane - CAP < n1c));
        const float cv = valid ? CVAL[row * CAP2 + lane] : -3.402823466e38f;
        const int   ci = valid ? (int)CIDX[row * CAP2 + lane] : 0;
        float emax = cv;
        #pragma unroll
        for (int off = 32; off; off >>= 1) emax = fmaxf(emax, __shfl_xor(emax, off));
        const unsigned long long ball2 = __ballot(valid && cv > emax - 1.0f);
        const int n2 = (int)__popcll(ball2);
        const int d4 = lane * 4;
        float tau;
        if (n2 == 1) {                         // weight exactly 1 on argmax
            const int si = __shfl(ci, __ffsll((unsigned long long)ball2) - 1);
            *(float4*)(Out + ((size_t)(b * TT + t0 + row)) * DD + d4) =
                *(const float4*)(Vb + (size_t)si * DD + d4);
            continue;
        } else if (n2 == 2) {                  // closed-form tau
            const int i1 = __ffsll((unsigned long long)ball2) - 1;
            const unsigned long long b3 = ball2 & (ball2 - 1);
            const int i2 = __ffsll((unsigned long long)b3) - 1;
            const float a = __shfl(cv, i1), c2 = __shfl(cv, i2);
            const float hv = fmaxf(a, c2), lv2 = fminf(a, c2);
            const float d = hv - lv2;
            tau = 0.5f * ((hv + lv2) - sqrtf(2.0f - d * d));
        } else {
            float lo = emax - 1.0f, hi = emax;
            for (int it = 0; it < NITER; ++it) {
                const float tm = 0.5f * (lo + hi);
                const float tt2 = fmaxf(cv - tm, 0.0f);
                float s = tt2 * tt2;
                #pragma unroll
                for (int off = 32; off; off >>= 1) s += __shfl_xor(s, off);
                const bool gt = s > 1.0f;
                lo = gt ? tm : lo;
                hi = gt ? hi : tm;
            }
            tau = 0.5f * (lo + hi);
        }
        const float tt2 = fmaxf(cv - tau, 0.0f);
        float s = tt2 * tt2;
        #pragma unroll
        for (int off = 32; off; off >>= 1) s += __shfl_xor(s, off);
        const float w = tt2 * tt2 / s;         // exact renormalization
        unsigned long long bw = __ballot(w > 0.0f && valid);
        float4 o = make_float4(0.f, 0.f, 0.f, 0.f);
        while (bw) {
            const int i = __ffsll((unsigned long long)bw) - 1;
            bw &= bw - 1;
            const float wi = __shfl(w, i);
            const int   si = __shfl(ci, i);
            const float4 v = *(const float4*)(Vb + (size_t)si * DD + d4);
            o.x = fmaf(wi, v.x, o.x); o.y = fmaf(wi, v.y, o.y);
            o.z = fmaf(wi, v.z, o.z); o.w = fmaf(wi, v.w, o.w);
        }
        *(float4*)(Out + ((size_t)(b * TT + t0 + row)) * DD + d4) = o;
    }
}

// ---------------- round-1 kernel kept as ws-size fallback ----------------
#define DOT4(A, Kv, Qv) \
    A = fmaf((Qv).x, (Kv).x, fmaf((Qv).y, (Kv).y, fmaf((Qv).z, (Kv).z, fmaf((Qv).w, (Kv).w, (A)))))

__launch_bounds__(256, 2)
__global__ void entmax_fallback_kernel(const float* __restrict__ Q,
                                       const float* __restrict__ V,
                                       const float* __restrict__ K,
                                       float* __restrict__ Out) {
    extern __shared__ float zshf[];
    const int tid = threadIdx.x;
    const int b   = blockIdx.x >> 8;
    const int t0  = (blockIdx.x & 255) * 8;
    const float* Qb = Q + ((size_t)b * TT + t0) * DD;
    const float* Kb = K + (size_t)b * TT * DD;
    const float* Vb = V + (size_t)b * TT * DD;
    for (int g = 0; g < 2; ++g) {
        const int c0 = (g << 10) + tid;
        const float* k0 = Kb + (size_t)c0 * DD;
        float4 acc[8];
        #pragma unroll
        for (int r = 0; r < 8; ++r) acc[r] = make_float4(0.f, 0.f, 0.f, 0.f);
        for (int d = 0; d < DD; d += 4) {
            const float4 ka = *(const float4*)(k0 + d);
            const float4 kb = *(const float4*)(k0 + 256 * DD + d);
            const float4 kc = *(const float4*)(k0 + 512 * DD + d);
            const float4 kd = *(const float4*)(k0 + 768 * DD + d);
            #pragma unroll
            for (int r = 0; r < 8; ++r) {
                const float4 qv = *(const float4*)(Qb + r * DD + d);
                DOT4(acc[r].x, ka, qv); DOT4(acc[r].y, kb, qv);
                DOT4(acc[r].z, kc, qv); DOT4(acc[r].w, kd, qv);
            }
        }
        #pragma unroll
        for (int r = 0; r < 8; ++r) {
            zshf[r * TT + c0      ] = 0.5f * acc[r].x;
            zshf[r * TT + c0 + 256] = 0.5f * acc[r].y;
            zshf[r * TT + c0 + 512] = 0.5f * acc[r].z;
            zshf[r * TT + c0 + 768] = 0.5f * acc[r].w;
        }
    }
    __syncthreads();
    {
        const int wid = tid >> 6, lane = tid & 63;
        for (int rr = 0; rr < 2; ++rr) {
            const int r = wid * 2 + rr;
            float* z = zshf + r * TT;
            float zv[32];
            float m = -3.402823466e38f;
            #pragma unroll
            for (int j = 0; j < 32; ++j) { zv[j] = z[lane + (j << 6)]; m = fmaxf(m, zv[j]); }
            #pragma unroll
            for (int off = 32; off; off >>= 1) m = fmaxf(m, __shfl_xor(m, off));
            float lo = m - 1.0f, hi = m;
            for (int it = 0; it < NITER; ++it) {
                const float tau = 0.5f * (lo + hi);
                float s = 0.f;
                #pragma unroll
                for (int j = 0; j < 32; ++j) { float t = fmaxf(zv[j] - tau, 0.f); s = fmaf(t, t, s); }
                #pragma unroll
                for (int off = 32; off; off >>= 1) s += __shfl_xor(s, off);
                const bool gt = (s - 1.0f) > 0.0f;
                lo = gt ? tau : lo; hi = gt ? hi : tau;
            }
            const float tau = 0.5f * (lo + hi);
            float ssum = 0.f;
            #pragma unroll
            for (int j = 0; j < 32; ++j) { float t = fmaxf(zv[j] - tau, 0.f); ssum = fmaf(t, t, ssum); }
            #pragma unroll
            for (int off = 32; off; off >>= 1) ssum += __shfl_xor(ssum, off);
            const float inv = 1.0f / ssum;
            #pragma unroll
            for (int j = 0; j < 32; ++j) {
                float t = fmaxf(zv[j] - tau, 0.f);
                z[lane + (j << 6)] = t * t * inv;
            }
        }
    }
    __syncthreads();
    {
        const int d2 = (tid & 127) * 2;
        const int sg = tid >> 7;
        float2 acc[8];
        #pragma unroll
        for (int r = 0; r < 8; ++r) acc[r] = make_float2(0.f, 0.f);
        for (int sc = 0; sc < TT; sc += 8) {
            const int s0 = sc + sg * 4;
            float4 w4[8];
            #pragma unroll
            for (int r = 0; r < 8; ++r) w4[r] = *(const float4*)&zshf[r * TT + s0];
            #pragma unroll
            for (int js = 0; js < 4; ++js) {
                const float2 v = *(const float2*)(Vb + (size_t)(s0 + js) * DD + d2);
                #pragma unroll
                for (int r = 0; r < 8; ++r) {
                    const float wv = (js == 0) ? w4[r].x : (js == 1) ? w4[r].y
                                   : (js == 2) ? w4[r].z : w4[r].w;
                    acc[r].x = fmaf(wv, v.x, acc[r].x);
                    acc[r].y = fmaf(wv, v.y, acc[r].y);
                }
            }
        }
        __syncthreads();
        float* part = zshf;
        if (sg == 1) {
            #pragma unroll
            for (int r = 0; r < 8; ++r) *(float2*)&part[r * DD + d2] = acc[r];
        }
        __syncthreads();
        if (sg == 0) {
            #pragma unroll
            for (int r = 0; r < 8; ++r) {
                const float2 p = *(const float2*)&part[r * DD + d2];
                float2 o; o.x = acc[r].x + p.x; o.y = acc[r].y + p.y;
                *(float2*)&Out[((size_t)b * TT + t0 + r) * DD + d2] = o;
            }
        }
    }
}

extern "C" void kernel_launch(void* const* d_in, const int* in_sizes, int n_in,
                              void* d_out, int out_size, void* d_ws, size_t ws_size,
                              hipStream_t stream) {
    const float* Q = (const float*)d_in[0];   // query
    const float* V = (const float*)d_in[1];   // value (dict order!)
    const float* K = (const float*)d_in[2];   // key
    float* Out = (float*)d_out;
    const int B = in_sizes[0] / (TT * DD);
    const size_t NE = (size_t)B * TT * DD;
    const size_t need = NE * 2;               // Kh bf16

    if (ws_size < need) {                     // defensive fallback (round-1 kernel)
        entmax_fallback_kernel<<<dim3(B * (TT / 8)), 256, 8 * TT * sizeof(float), stream>>>(
            Q, V, K, Out);
        return;
    }

    unsigned short* Kh = (unsigned short*)d_ws;
    split_k_kernel<<<2048, 256, 0, stream>>>(K, Kh, (int)(NE / 4));

    const int nwg = B * (TT / RQB);           // 256 for B=16 -> 1 block/CU, 16 waves
    (void)hipFuncSetAttribute((const void*)entmax_screen_kernel,
                              hipFuncAttributeMaxDynamicSharedMemorySize, LDS_SZ);
    entmax_screen_kernel<<<dim3(nwg), NT, LDS_SZ, stream>>>(Q, Kh, K, V, Out, nwg);
}

// Round 8
// 134.977 us; speedup vs baseline: 3.6508x; 3.6508x over previous
//
#include <hip/hip_runtime.h>

#define TT 2048     // sequence length
#define DD 256      // head dim
#define RQB 128     // q-rows per block (8 waves x 16)
#define NT 512      // 8 waves
#define KB 128      // K-cols per LDS tile (64 KB)
#define NTILE (TT / KB)   // 16
#define NITER 30
#define CAP 28      // stored candidates per row

// LDS byte layout (staging: 2 x 64 KB double buffer at offset 0)
#define L_CIDX 131072                      // u16 [RQB][CAP] = 7 KB
#define L_CVAL (L_CIDX + RQB * CAP * 2)    // f32 [RQB][CAP] = 14 KB
#define L_CNT  (L_CVAL + RQB * CAP * 4)    // int [RQB]
#define L_SLOT (L_CNT + RQB * 4)           // u16 [8][16*CAP] = 7 KB
#define L_OVF  (L_SLOT + 8 * 16 * CAP * 2)
#define LDS_SZ (L_OVF + 16)                // 160272 B <= 163840 (160 KiB)

typedef __attribute__((ext_vector_type(4))) float f32x4;
typedef __attribute__((ext_vector_type(8))) short short8;

__device__ inline unsigned short f2bf(float x) {     // RTN fp32 -> bf16
    unsigned u = __float_as_uint(x);
    return (unsigned short)((u + 0x7fffu + ((u >> 16) & 1u)) >> 16);
}
__device__ inline float bf2f(unsigned short h) {
    return __uint_as_float((unsigned)h << 16);
}

__device__ __forceinline__ void gload16(const void* g, void* l) {
    __builtin_amdgcn_global_load_lds(
        (const __attribute__((address_space(1))) void*)g,
        (__attribute__((address_space(3))) void*)l, 16, 0, 0);
}

// max over each 16-lane group via DPP (VALU-only, no LDS-pipe traffic)
__device__ __forceinline__ float dppmax16(float m) {
    int a = __builtin_amdgcn_update_dpp(__float_as_int(m), __float_as_int(m),
                                        0xB1, 0xF, 0xF, false);   // quad_perm [1,0,3,2]
    m = fmaxf(m, __int_as_float(a));
    a = __builtin_amdgcn_update_dpp(__float_as_int(m), __float_as_int(m),
                                    0x4E, 0xF, 0xF, false);       // quad_perm [2,3,0,1]
    m = fmaxf(m, __int_as_float(a));
    a = __builtin_amdgcn_update_dpp(__float_as_int(m), __float_as_int(m),
                                    0x141, 0xF, 0xF, false);      // row_half_mirror
    m = fmaxf(m, __int_as_float(a));
    a = __builtin_amdgcn_update_dpp(__float_as_int(m), __float_as_int(m),
                                    0x140, 0xF, 0xF, false);      // row_mirror
    m = fmaxf(m, __int_as_float(a));
    return m;
}

// ---------------- helper: K -> 0.5*K bf16 (screening operand) ----------------
__global__ __launch_bounds__(256) void split_k_kernel(const float* __restrict__ K,
        unsigned short* __restrict__ Kh, int n4) {
    int i = blockIdx.x * 256 + threadIdx.x;
    const int stride = gridDim.x * 256;
    for (; i < n4; i += stride) {
        float4 v = ((const float4*)K)[i];
        unsigned short h0 = f2bf(0.5f * v.x), h1 = f2bf(0.5f * v.y);
        unsigned short h2 = f2bf(0.5f * v.z), h3 = f2bf(0.5f * v.w);
        uint2 hv;
        hv.x = (unsigned)h0 | ((unsigned)h1 << 16);
        hv.y = (unsigned)h2 | ((unsigned)h3 << 16);
        ((uint2*)Kh)[i] = hv;
    }
}

// ---------------- main fused kernel ----------------
__launch_bounds__(NT, 2)
__global__ void entmax_screen_kernel(const float* __restrict__ Q,
                                     const unsigned short* __restrict__ Kh,
                                     const float* __restrict__ Kf,
                                     const float* __restrict__ V,
                                     float* __restrict__ Out,
                                     int nwg) {
    extern __shared__ char smem[];
    unsigned short* CIDX = (unsigned short*)(smem + L_CIDX);
    float*          CVAL = (float*)(smem + L_CVAL);
    int*            CNT  = (int*)(smem + L_CNT);
    unsigned short* SLOT = (unsigned short*)(smem + L_SLOT);
    int*            POVF = (int*)(smem + L_OVF);

    const int tid = threadIdx.x;
    const int wid = tid >> 6, lane = tid & 63;
    const int l15 = lane & 15, ag = lane >> 4;
    const int wrow0 = wid * 16;

    // XCD-bijective swizzle (nwg = B*16 = 256, divisible by 8)
    const int lb = (blockIdx.x & 7) * (nwg >> 3) + (blockIdx.x >> 3);
    const int b  = lb >> 4;
    const int t0 = (lb & 15) * RQB;

    const char* KhB = (const char*)(Kh + (size_t)b * TT * DD);

    if (tid == 0) *POVF = 0;

    // ---- A-fragments: 16 Q rows per wave, single bf16 ----
    short8 ah[8];
    {
        const float* qr = Q + (size_t)(b * TT + t0 + wrow0 + l15) * DD;
        #pragma unroll
        for (int kk = 0; kk < 8; ++kk) {
            const int d0 = kk * 32 + ag * 8;
            float4 qa = *(const float4*)(qr + d0);
            float4 qb = *(const float4*)(qr + d0 + 4);
            float qf[8] = {qa.x, qa.y, qa.z, qa.w, qb.x, qb.y, qb.z, qb.w};
            #pragma unroll
            for (int i = 0; i < 8; ++i) ah[kk][i] = (short)f2bf(qf[i]);
        }
    }

    // ---- staging: 128 cols x 512 B = 64 KB/tile; wave-uniform LDS dest,
    //      per-lane inverse-swizzled global source ----
    auto STAGE = [&](int tile, int buf) {
        #pragma unroll
        for (int j = 0; j < 8; ++j) {
            const int ofs = wid * 8192 + j * 1024 + lane * 16;  // linear byte in tile
            const int cl = ofs >> 9, wb = ofs & 511;
            const size_t gb = ((size_t)((tile << 7) + cl) << 9) +
                              (size_t)(wb ^ ((cl & 7) << 4));
            gload16(KhB + gb, smem + buf * 65536 + wid * 8192 + j * 1024);
        }
    };

    STAGE(0, 0);
    __syncthreads();

    const unsigned long long grpmask = 0xFFFFULL << (ag * 16);
    const unsigned long long lowmask = (lane == 0) ? 0ULL : ((~0ULL) >> (64 - lane));
    float rmax[4];
    int   base[4];
    #pragma unroll
    for (int r = 0; r < 4; ++r) { rmax[r] = -3.402823466e38f; base[r] = 0; }

    // ---------------- screening pass: 16 tiles of 128 cols ----------------
    for (int t = 0; t < NTILE; ++t) {
        const int cur = t & 1;
        if (t + 1 < NTILE) STAGE(t + 1, cur ^ 1);
        f32x4 acc[8];
        #pragma unroll
        for (int ct = 0; ct < 8; ++ct)
            #pragma unroll
            for (int r = 0; r < 4; ++r) acc[ct][r] = 0.0f;
        #pragma unroll
        for (int kk = 0; kk < 8; ++kk) {
            short8 bh[8];
            #pragma unroll
            for (int ct = 0; ct < 8; ++ct)
                bh[ct] = *(const short8*)(smem + cur * 65536 + (ct * 16 + l15) * 512 +
                                          (((kk * 64) + ag * 16) ^ ((l15 & 7) << 4)));
            #pragma unroll
            for (int ct = 0; ct < 8; ++ct)
                acc[ct] = __builtin_amdgcn_mfma_f32_16x16x32_bf16(ah[kk], bh[ct], acc[ct], 0, 0, 0);
        }
        // per-row-group running max (DPP) + early-out candidate append
        #pragma unroll
        for (int rg = 0; rg < 4; ++rg) {
            float m = acc[0][rg];
            #pragma unroll
            for (int ct = 1; ct < 8; ++ct) m = fmaxf(m, acc[ct][rg]);
            m = dppmax16(m);                     // uniform within 16-lane group
            rmax[rg] = fmaxf(rmax[rg], m);
            const float thr = rmax[rg] - 1.6f;   // slack covers bf16 screen error
            if (m > thr) {                       // tile holds a candidate for this group
                const int row = wrow0 + ag * 4 + rg;
                #pragma unroll
                for (int ct = 0; ct < 8; ++ct) {
                    const bool p = acc[ct][rg] > thr;
                    const unsigned long long ball = __ballot(p) & grpmask;
                    if (ball) {
                        const int rank = (int)__popcll(ball & lowmask);
                        if (p && base[rg] + rank < CAP)
                            CIDX[row * CAP + base[rg] + rank] =
                                (unsigned short)((t << 7) + ct * 16 + l15);
                        base[rg] += (int)__popcll(ball);
                    }
                }
            }
        }
        __syncthreads();
    }

    // publish counts
    #pragma unroll
    for (int rg = 0; rg < 4; ++rg) {
        if (l15 == 0) {
            CNT[wrow0 + ag * 4 + rg] = base[rg];
            if (base[rg] > CAP) *POVF = 1;
        }
    }
    __syncthreads();

    // ---------------- exact fp32 recompute of stored candidates ----------------
    int c = 0;
    if (lane < 16) {
        const int cc = CNT[wrow0 + lane];
        c = cc > CAP ? CAP : cc;
    }
    int x = c;
    #pragma unroll
    for (int off = 1; off < 16; off <<= 1) {
        const int v = __shfl_up(x, off);
        if ((lane & 15) >= off) x += v;
    }
    const int pfx = x - c;
    const int total = __shfl(x, 15);
    if (lane < 16)
        for (int i = 0; i < c; ++i)
            SLOT[wid * (16 * CAP) + pfx + i] = (unsigned short)((lane << 8) | i);
    __syncthreads();

    {
        const float* Qb = Q + (size_t)(b * TT + t0 + wrow0) * DD;
        const float* Kb = Kf + (size_t)b * TT * DD;
        for (int bs = 0; bs < total; bs += 8) {
            float4 qv[8], kv[8];
            int rl[8], ii[8];
            #pragma unroll
            for (int u = 0; u < 8; ++u) {
                const int s = bs + u;
                const int e = (s < total) ? (int)SLOT[wid * (16 * CAP) + s] : 0;
                rl[u] = e >> 8; ii[u] = e & 255;
                const int col = (s < total) ? (int)CIDX[(wrow0 + rl[u]) * CAP + ii[u]] : 0;
                qv[u] = *(const float4*)(Qb + (size_t)rl[u] * DD + lane * 4);
                kv[u] = *(const float4*)(Kb + (size_t)col * DD + lane * 4);
            }
            float sm[8];
            #pragma unroll
            for (int u = 0; u < 8; ++u) {
                float d = qv[u].x * kv[u].x;
                d = fmaf(qv[u].y, kv[u].y, d);
                d = fmaf(qv[u].z, kv[u].z, d);
                d = fmaf(qv[u].w, kv[u].w, d);
                sm[u] = d;
            }
            #pragma unroll
            for (int off = 32; off; off >>= 1)
                #pragma unroll
                for (int u = 0; u < 8; ++u) sm[u] += __shfl_xor(sm[u], off);
            #pragma unroll
            for (int u = 0; u < 8; ++u)
                if (lane == u && bs + u < total)
                    CVAL[(wrow0 + rl[u]) * CAP + ii[u]] = 0.5f * sm[u];
        }
    }
    __syncthreads();

    // ---------------- slow path (CAP overflow; ~never) ----------------
    if (*POVF) {
        if (wid == 0) {
            float* fbz = (float*)smem;          // staging buffers are dead
            for (int r = 0; r < RQB; ++r) {
                if (CNT[r] <= CAP) continue;
                const float* qr = Q + (size_t)(b * TT + t0 + r) * DD;
                const float* Kb = Kf + (size_t)b * TT * DD;
                for (int cc2 = lane; cc2 < TT; cc2 += 64) {
                    const float* kr = Kb + (size_t)cc2 * DD;
                    float a = 0.0f;
                    for (int d = 0; d < DD; ++d) a = fmaf(qr[d], kr[d], a);
                    fbz[cc2] = 0.5f * a;
                }
                __threadfence_block();
                float m = -3.402823466e38f;
                for (int cc2 = lane; cc2 < TT; cc2 += 64) m = fmaxf(m, fbz[cc2]);
                #pragma unroll
                for (int off = 32; off; off >>= 1) m = fmaxf(m, __shfl_xor(m, off));
                float lo = m - 1.0f, hi = m, tau;
                for (int it = 0; it < NITER; ++it) {
                    tau = 0.5f * (lo + hi);
                    float s = 0.0f;
                    for (int cc2 = lane; cc2 < TT; cc2 += 64) {
                        const float tt2 = fmaxf(fbz[cc2] - tau, 0.0f);
                        s = fmaf(tt2, tt2, s);
                    }
                    #pragma unroll
                    for (int off = 32; off; off >>= 1) s += __shfl_xor(s, off);
                    const bool gt = s > 1.0f;
                    lo = gt ? tau : lo;
                    hi = gt ? hi : tau;
                }
                tau = 0.5f * (lo + hi);
                float ssum = 0.0f;
                for (int cc2 = lane; cc2 < TT; cc2 += 64) {
                    const float tt2 = fmaxf(fbz[cc2] - tau, 0.0f);
                    ssum = fmaf(tt2, tt2, ssum);
                }
                #pragma unroll
                for (int off = 32; off; off >>= 1) ssum += __shfl_xor(ssum, off);
                const float inv = 1.0f / ssum;
                const int d4 = lane * 4;
                float4 o = make_float4(0.f, 0.f, 0.f, 0.f);
                for (int s = 0; s < TT; ++s) {
                    const float tt2 = fmaxf(fbz[s] - tau, 0.0f);
                    const float w = tt2 * tt2 * inv;
                    if (w > 0.0f) {
                        const float4 v = *(const float4*)(V + ((size_t)b * TT + s) * DD + d4);
                        o.x = fmaf(w, v.x, o.x); o.y = fmaf(w, v.y, o.y);
                        o.z = fmaf(w, v.z, o.z); o.w = fmaf(w, v.w, o.w);
                    }
                }
                *(float4*)(Out + ((size_t)(b * TT + t0 + r)) * DD + d4) = o;
                if (lane == 0) CNT[r] = -1;
                __threadfence_block();
            }
        }
        __syncthreads();
    }

    // ---------------- scalar per-lane tau + weights (lane r owns row wrow0+r) ----------------
    {
        const int myrow = wrow0 + (lane & 15);        // lanes 16+ duplicate (benign)
        const int nRaw = CNT[myrow];
        const int n = (nRaw < 0) ? 0 : (nRaw > CAP ? CAP : nRaw);
        float cvr[CAP];
        #pragma unroll
        for (int i = 0; i < CAP; ++i)
            cvr[i] = (i < n) ? CVAL[myrow * CAP + i] : -3.0e30f;
        float emax = cvr[0];
        #pragma unroll
        for (int i = 1; i < CAP; ++i) emax = fmaxf(emax, cvr[i]);
        float lo = emax - 1.0f, hi = emax;
        for (int it = 0; it < NITER; ++it) {
            const float tau = 0.5f * (lo + hi);
            float s = 0.0f;
            #pragma unroll
            for (int i = 0; i < CAP; ++i) {
                const float tt2 = fmaxf(cvr[i] - tau, 0.0f);
                s = fmaf(tt2, tt2, s);
            }
            const bool gt = s > 1.0f;
            lo = gt ? tau : lo;
            hi = gt ? hi : tau;
        }
        const float tau = 0.5f * (lo + hi);
        float ssum = 0.0f;
        #pragma unroll
        for (int i = 0; i < CAP; ++i) {
            const float tt2 = fmaxf(cvr[i] - tau, 0.0f);
            ssum = fmaf(tt2, tt2, ssum);
        }
        const float inv = 1.0f / ssum;                // valid rows: ssum > 0
        if (lane < 16 && n > 0) {
            for (int i = 0; i < n; ++i) {
                const float tt2 = fmaxf(cvr[i] - tau, 0.0f);
                CVAL[myrow * CAP + i] = tt2 * tt2 * inv;   // normalized weight
            }
        }
    }
    // wave-local writes read by same wave below; lgkmcnt ordering is automatic

    // ---------------- sparse PV via broadcast LDS reads ----------------
    const float* Vb = V + (size_t)b * TT * DD;
    for (int j = 0; j < 16; ++j) {
        const int row = wrow0 + j;
        const int n = CNT[row];
        if (n < 0) continue;                   // slow path handled
        const int d4 = lane * 4;
        float4 o = make_float4(0.f, 0.f, 0.f, 0.f);
        for (int i = 0; i < n; ++i) {
            const float wi = CVAL[row * CAP + i];    // LDS broadcast (uniform addr)
            if (wi > 0.0f) {
                const int si = (int)CIDX[row * CAP + i];
                const float4 v = *(const float4*)(Vb + (size_t)si * DD + d4);
                o.x = fmaf(wi, v.x, o.x); o.y = fmaf(wi, v.y, o.y);
                o.z = fmaf(wi, v.z, o.z); o.w = fmaf(wi, v.w, o.w);
            }
        }
        *(float4*)(Out + ((size_t)(b * TT + t0 + row)) * DD + d4) = o;
    }
}

// ---------------- round-1 kernel kept as ws-size fallback ----------------
#define DOT4(A, Kv, Qv) \
    A = fmaf((Qv).x, (Kv).x, fmaf((Qv).y, (Kv).y, fmaf((Qv).z, (Kv).z, fmaf((Qv).w, (Kv).w, (A)))))

__launch_bounds__(256, 2)
__global__ void entmax_fallback_kernel(const float* __restrict__ Q,
                                       const float* __restrict__ V,
                                       const float* __restrict__ K,
                                       float* __restrict__ Out) {
    extern __shared__ float zshf[];
    const int tid = threadIdx.x;
    const int b   = blockIdx.x >> 8;
    const int t0  = (blockIdx.x & 255) * 8;
    const float* Qb = Q + ((size_t)b * TT + t0) * DD;
    const float* Kb = K + (size_t)b * TT * DD;
    const float* Vb = V + (size_t)b * TT * DD;
    for (int g = 0; g < 2; ++g) {
        const int c0 = (g << 10) + tid;
        const float* k0 = Kb + (size_t)c0 * DD;
        float4 acc[8];
        #pragma unroll
        for (int r = 0; r < 8; ++r) acc[r] = make_float4(0.f, 0.f, 0.f, 0.f);
        for (int d = 0; d < DD; d += 4) {
            const float4 ka = *(const float4*)(k0 + d);
            const float4 kb = *(const float4*)(k0 + 256 * DD + d);
            const float4 kc = *(const float4*)(k0 + 512 * DD + d);
            const float4 kd = *(const float4*)(k0 + 768 * DD + d);
            #pragma unroll
            for (int r = 0; r < 8; ++r) {
                const float4 qv = *(const float4*)(Qb + r * DD + d);
                DOT4(acc[r].x, ka, qv); DOT4(acc[r].y, kb, qv);
                DOT4(acc[r].z, kc, qv); DOT4(acc[r].w, kd, qv);
            }
        }
        #pragma unroll
        for (int r = 0; r < 8; ++r) {
            zshf[r * TT + c0      ] = 0.5f * acc[r].x;
            zshf[r * TT + c0 + 256] = 0.5f * acc[r].y;
            zshf[r * TT + c0 + 512] = 0.5f * acc[r].z;
            zshf[r * TT + c0 + 768] = 0.5f * acc[r].w;
        }
    }
    __syncthreads();
    {
        const int wid = tid >> 6, lane = tid & 63;
        for (int rr = 0; rr < 2; ++rr) {
            const int r = wid * 2 + rr;
            float* z = zshf + r * TT;
            float zv[32];
            float m = -3.402823466e38f;
            #pragma unroll
            for (int j = 0; j < 32; ++j) { zv[j] = z[lane + (j << 6)]; m = fmaxf(m, zv[j]); }
            #pragma unroll
            for (int off = 32; off; off >>= 1) m = fmaxf(m, __shfl_xor(m, off));
            float lo = m - 1.0f, hi = m;
            for (int it = 0; it < NITER; ++it) {
                const float tau = 0.5f * (lo + hi);
                float s = 0.f;
                #pragma unroll
                for (int j = 0; j < 32; ++j) { float t = fmaxf(zv[j] - tau, 0.f); s = fmaf(t, t, s); }
                #pragma unroll
                for (int off = 32; off; off >>= 1) s += __shfl_xor(s, off);
                const bool gt = (s - 1.0f) > 0.0f;
                lo = gt ? tau : lo; hi = gt ? hi : tau;
            }
            const float tau = 0.5f * (lo + hi);
            float ssum = 0.f;
            #pragma unroll
            for (int j = 0; j < 32; ++j) { float t = fmaxf(zv[j] - tau, 0.f); ssum = fmaf(t, t, ssum); }
            #pragma unroll
            for (int off = 32; off; off >>= 1) ssum += __shfl_xor(ssum, off);
            const float inv = 1.0f / ssum;
            #pragma unroll
            for (int j = 0; j < 32; ++j) {
                float t = fmaxf(zv[j] - tau, 0.f);
                z[lane + (j << 6)] = t * t * inv;
            }
        }
    }
    __syncthreads();
    {
        const int d2 = (tid & 127) * 2;
        const int sg = tid >> 7;
        float2 acc[8];
        #pragma unroll
        for (int r = 0; r < 8; ++r) acc[r] = make_float2(0.f, 0.f);
        for (int sc = 0; sc < TT; sc += 8) {
            const int s0 = sc + sg * 4;
            float4 w4[8];
            #pragma unroll
            for (int r = 0; r < 8; ++r) w4[r] = *(const float4*)&zshf[r * TT + s0];
            #pragma unroll
            for (int js = 0; js < 4; ++js) {
                const float2 v = *(const float2*)(Vb + (size_t)(s0 + js) * DD + d2);
                #pragma unroll
                for (int r = 0; r < 8; ++r) {
                    const float wv = (js == 0) ? w4[r].x : (js == 1) ? w4[r].y
                                   : (js == 2) ? w4[r].z : w4[r].w;
                    acc[r].x = fmaf(wv, v.x, acc[r].x);
                    acc[r].y = fmaf(wv, v.y, acc[r].y);
                }
            }
        }
        __syncthreads();
        float* part = zshf;
        if (sg == 1) {
            #pragma unroll
            for (int r = 0; r < 8; ++r) *(float2*)&part[r * DD + d2] = acc[r];
        }
        __syncthreads();
        if (sg == 0) {
            #pragma unroll
            for (int r = 0; r < 8; ++r) {
                const float2 p = *(const float2*)&part[r * DD + d2];
                float2 o; o.x = acc[r].x + p.x; o.y = acc[r].y + p.y;
                *(float2*)&Out[((size_t)b * TT + t0 + r) * DD + d2] = o;
            }
        }
    }
}

extern "C" void kernel_launch(void* const* d_in, const int* in_sizes, int n_in,
                              void* d_out, int out_size, void* d_ws, size_t ws_size,
                              hipStream_t stream) {
    const float* Q = (const float*)d_in[0];   // query
    const float* V = (const float*)d_in[1];   // value (dict order!)
    const float* K = (const float*)d_in[2];   // key
    float* Out = (float*)d_out;
    const int B = in_sizes[0] / (TT * DD);
    const size_t NE = (size_t)B * TT * DD;
    const size_t need = NE * 2;               // Kh bf16

    if (ws_size < need) {                     // defensive fallback (round-1 kernel)
        entmax_fallback_kernel<<<dim3(B * (TT / 8)), 256, 8 * TT * sizeof(float), stream>>>(
            Q, V, K, Out);
        return;
    }

    unsigned short* Kh = (unsigned short*)d_ws;
    split_k_kernel<<<2048, 256, 0, stream>>>(K, Kh, (int)(NE / 4));

    const int nwg = B * (TT / RQB);           // 256 for B=16 -> 1 block/CU, 8 waves
    (void)hipFuncSetAttribute((const void*)entmax_screen_kernel,
                              hipFuncAttributeMaxDynamicSharedMemorySize, LDS_SZ);
    entmax_screen_kernel<<<dim3(nwg), NT, LDS_SZ, stream>>>(Q, Kh, K, V, Out, nwg);
}